// Round 8
// baseline (153.867 us; speedup 1.0000x reference)
//
#include <hip/hip_runtime.h>
#include <hip/hip_bf16.h>

typedef __bf16 bf16_t;
typedef __bf16 bf16x8 __attribute__((ext_vector_type(8)));
typedef __bf16 bf16x4 __attribute__((ext_vector_type(4)));
typedef float  floatx4 __attribute__((ext_vector_type(4)));

static __device__ __forceinline__ floatx4 mfma16(bf16x8 a, bf16x8 b, floatx4 c) {
  return __builtin_amdgcn_mfma_f32_16x16x32_bf16(a, b, c, 0, 0, 0);
}

// async global->LDS, 16B per lane; LDS dest = wave-uniform base + lane*16.
typedef __attribute__((address_space(3))) void lds_vp;
typedef __attribute__((address_space(1))) void glb_vp;
#define GLDS16(g, l) \
  __builtin_amdgcn_global_load_lds((glb_vp*)(g), (lds_vp*)(l), 16, 0, 0)

// ---------------- fused fp32 -> bf16 convert (x, W_QKV, W_O) ----------------
__global__ void cvt_all_kernel(const float* __restrict__ x,
                               const float* __restrict__ wqkv,
                               const float* __restrict__ wo,
                               bf16_t* __restrict__ xb,
                               bf16_t* __restrict__ wqkvb,
                               bf16_t* __restrict__ wob) {
  int i = blockIdx.x * blockDim.x + threadIdx.x;     // 0..1310719 float4s
  const float4* src; bf16x4* dst; int off;
  if (i < 1048576)      { src = (const float4*)x;    dst = (bf16x4*)xb;    off = i; }
  else if (i < 1245184) { src = (const float4*)wqkv; dst = (bf16x4*)wqkvb; off = i - 1048576; }
  else                  { src = (const float4*)wo;   dst = (bf16x4*)wob;   off = i - 1245184; }
  float4 v = src[off];
  bf16x4 o;
  o[0] = (bf16_t)v.x; o[1] = (bf16_t)v.y; o[2] = (bf16_t)v.z; o[3] = (bf16_t)v.w;
  dst[off] = o;
}

// ---------------- QKV GEMM: C(M,N) = A(M,K) * B(N,K)^T ----------------
__global__ __launch_bounds__(256) void gemm_qkv(
    const bf16_t* __restrict__ A, const bf16_t* __restrict__ B,
    bf16_t* __restrict__ Qo, bf16_t* __restrict__ Ko, bf16_t* __restrict__ Vto)
{
  __shared__ __align__(16) bf16_t As[2][128 * 64];
  __shared__ __align__(16) bf16_t Bs[2][128 * 64];
  const int tid  = threadIdx.x;
  const int lane = tid & 63;
  const int w    = tid >> 6;
  const int quad = lane >> 4;
  const int l15  = lane & 15;
  const int l7   = lane & 7;
  const int wm   = w & 1;
  const int wn   = w >> 1;
  const int K    = 512;

  floatx4 acc[4][4];
  #pragma unroll
  for (int i = 0; i < 4; ++i)
    #pragma unroll
    for (int j = 0; j < 4; ++j)
      acc[i][j] = (floatx4){0.f, 0.f, 0.f, 0.f};

  const bf16_t* Ab = A + (size_t)blockIdx.x * 128 * K;
  const bf16_t* Bb = B + (size_t)blockIdx.y * 128 * K;

  auto stage = [&](int buf, int k0) {
    #pragma unroll
    for (int i = 0; i < 4; ++i) {
      int c = tid + 256 * i;
      int row = c >> 3, colc = c & 7;
      int gofs = ((colc ^ (row & 7)) << 3);
      GLDS16(&Ab[(size_t)row * K + k0 + gofs], &As[buf][c * 8]);
      GLDS16(&Bb[(size_t)row * K + k0 + gofs], &Bs[buf][c * 8]);
    }
  };

  stage(0, 0);
  for (int it = 0; it < 8; ++it) {
    const int cur = it & 1;
    __syncthreads();
    if (it + 1 < 8) stage(cur ^ 1, (it + 1) << 6);
    #pragma unroll
    for (int ks = 0; ks < 2; ++ks) {
      bf16x8 af[4], bfr[4];
      #pragma unroll
      for (int t = 0; t < 4; ++t) {
        af[t]  = *(const bf16x8*)&As[cur][(wm * 64 + t * 16 + l15) * 64 +
                                         (((ks * 4 + quad) ^ l7) << 3)];
        bfr[t] = *(const bf16x8*)&Bs[cur][(wn * 64 + t * 16 + l15) * 64 +
                                         (((ks * 4 + quad) ^ l7) << 3)];
      }
      #pragma unroll
      for (int mt = 0; mt < 4; ++mt)
        #pragma unroll
        for (int nt = 0; nt < 4; ++nt)
          acc[mt][nt] = mfma16(af[mt], bfr[nt], acc[mt][nt]);
    }
  }

  if (blockIdx.y < 8) {
    // ---- Q / K scatter epilogue ----
    #pragma unroll
    for (int mt = 0; mt < 4; ++mt) {
      #pragma unroll
      for (int nt = 0; nt < 4; ++nt) {
        #pragma unroll
        for (int r = 0; r < 4; ++r) {
          int m = blockIdx.x * 128 + wm * 64 + mt * 16 + quad * 4 + r;
          int n = blockIdx.y * 128 + wn * 64 + nt * 16 + l15;
          float v = acc[mt][nt][r];
          int b = m >> 12, t = m & 4095;
          int h = (n >> 6) & 7, d = n & 63;
          size_t bh = (size_t)(b * 8 + h);
          if (n < 512)   // fold 1/sqrt(64) * log2(e) -> softmax in log2 domain
            Qo[bh * 262144 + (size_t)t * 64 + d] = (bf16_t)(v * 0.18033688f);
          else
            Ko[bh * 262144 + (size_t)t * 64 + d] = (bf16_t)v;
        }
      }
    }
  } else {
    // ---- V epilogue: transpose through LDS (As region, 32 KB) ----
    __syncthreads();                       // everyone done reading As/Bs
    bf16_t* L = &As[0][0];                 // [n_local][m swizzled] 128x128
    #pragma unroll
    for (int mt = 0; mt < 4; ++mt)
      #pragma unroll
      for (int nt = 0; nt < 4; ++nt) {
        int n_l = wn * 64 + nt * 16 + l15;
        int mc  = wm * 8 + mt * 2 + (quad >> 1);     // m-chunk of 8
        bf16x4 v4;
        #pragma unroll
        for (int r = 0; r < 4; ++r) v4[r] = (bf16_t)acc[mt][nt][r];
        *(bf16x4*)&L[n_l * 128 + ((mc ^ (n_l & 15)) << 3) + (quad & 1) * 4] = v4;
      }
    __syncthreads();
    const int t0 = (blockIdx.x & 31) * 128;
    const int b  = blockIdx.x >> 5;
    #pragma unroll
    for (int i = 0; i < 8; ++i) {
      int c = tid + 256 * i;               // 0..2047: n_l = c>>4, tc = c&15
      int n_l = c >> 4, tc = c & 15;
      int h = ((blockIdx.y - 8) << 1) | (n_l >> 6);
      int d = n_l & 63;
      size_t bh = (size_t)(b * 8 + h);
      int base0 = (tc >> 2) * 32 + (tc & 3) * 4;
      bf16x4 lo = *(const bf16x4*)&L[n_l * 128 +
                     (((base0 >> 3) ^ (n_l & 15)) << 3) + (base0 & 7)];
      bf16x4 hi = *(const bf16x4*)&L[n_l * 128 +
                     ((((base0 + 16) >> 3) ^ (n_l & 15)) << 3) + (base0 & 7)];
      bf16x8 o;
      #pragma unroll
      for (int e = 0; e < 4; ++e) { o[e] = lo[e]; o[e + 4] = hi[e]; }
      *(bf16x8*)&Vto[bh * 262144 + (size_t)d * 4096 + t0 + tc * 8] = o;
    }
  }
}

// ---------------- output GEMM: out(8192,512) = Ob(8192,512) * Wo(512,512)^T ----
__global__ __launch_bounds__(256) void gemm_out(
    const bf16_t* __restrict__ A, const bf16_t* __restrict__ B,
    float* __restrict__ Cf)
{
  __shared__ __align__(16) bf16_t As[2][64 * 64];
  __shared__ __align__(16) bf16_t Bs[2][128 * 64];
  const int tid  = threadIdx.x;
  const int lane = tid & 63;
  const int w    = tid >> 6;               // 0..3, owns n-range w*32..+32
  const int quad = lane >> 4;
  const int l15  = lane & 15;
  const int l7   = lane & 7;

  floatx4 acc[4][2];
  #pragma unroll
  for (int i = 0; i < 4; ++i)
    #pragma unroll
    for (int j = 0; j < 2; ++j)
      acc[i][j] = (floatx4){0.f, 0.f, 0.f, 0.f};

  const bf16_t* Ab = A + (size_t)blockIdx.x * 64 * 512;
  const bf16_t* Bb = B + (size_t)blockIdx.y * 128 * 512;

  auto stage = [&](int buf, int k0) {
    #pragma unroll
    for (int i = 0; i < 2; ++i) {          // A: 512 chunks
      int c = tid + 256 * i;
      int row = c >> 3, colc = c & 7;
      GLDS16(&Ab[(size_t)row * 512 + k0 + ((colc ^ (row & 7)) << 3)],
             &As[buf][c * 8]);
    }
    #pragma unroll
    for (int i = 0; i < 4; ++i) {          // B: 1024 chunks
      int c = tid + 256 * i;
      int row = c >> 3, colc = c & 7;
      GLDS16(&Bb[(size_t)row * 512 + k0 + ((colc ^ (row & 7)) << 3)],
             &Bs[buf][c * 8]);
    }
  };

  stage(0, 0);
  for (int it = 0; it < 8; ++it) {
    const int cur = it & 1;
    __syncthreads();
    if (it + 1 < 8) stage(cur ^ 1, (it + 1) << 6);
    #pragma unroll
    for (int ks = 0; ks < 2; ++ks) {
      bf16x8 af[4], bfr[2];
      #pragma unroll
      for (int t = 0; t < 4; ++t)
        af[t]  = *(const bf16x8*)&As[cur][(t * 16 + l15) * 64 +
                                         (((ks * 4 + quad) ^ l7) << 3)];
      #pragma unroll
      for (int t = 0; t < 2; ++t)
        bfr[t] = *(const bf16x8*)&Bs[cur][(w * 32 + t * 16 + l15) * 64 +
                                         (((ks * 4 + quad) ^ l7) << 3)];
      #pragma unroll
      for (int mt = 0; mt < 4; ++mt)
        #pragma unroll
        for (int nt = 0; nt < 2; ++nt)
          acc[mt][nt] = mfma16(af[mt], bfr[nt], acc[mt][nt]);
    }
  }

  #pragma unroll
  for (int mt = 0; mt < 4; ++mt)
    #pragma unroll
    for (int nt = 0; nt < 2; ++nt)
      #pragma unroll
      for (int r = 0; r < 4; ++r) {
        int m = blockIdx.x * 64 + mt * 16 + quad * 4 + r;
        int n = blockIdx.y * 128 + w * 32 + nt * 16 + l15;
        Cf[(size_t)m * 512 + n] = acc[mt][nt][r];
      }
}

// ---- causal flash attention: wide-K uniform sequential-pair blocks ----
// 256 blocks x 512 threads, 1 block/CU (133 KB LDS). Block owns q-tile pair
// (qtA=31-x, qtB=x) of one bh, processed SEQUENTIALLY. Each iteration covers
// 256 k-rows; waves = {q-half(2)} x {k-quarter(4)}, each 64q x 64k = R3's
// proven inner body (72 MFMA / 16 b128 reads / 64 exp2). Iterations per block
// = ceil((2qtA+2)/4) + ceil((2qtB+2)/4) = 17 UNIFORM for every block -> no
// wall imbalance; wave-slot activity 130/136 = 96% (R3: 27-50%). Barriers
// drop 32 -> 17+epilogues. Staging volume per CU unchanged vs R3. Epilogue:
// k-quarter partials to LDS (128 KB alias of staging) + parallel sum+store.
// No-max log2-domain softmax (scores bounded, fp32-safe).
__global__ __launch_bounds__(512, 2) void attn_kernel(
    const bf16_t* __restrict__ Qg, const bf16_t* __restrict__ Kgl,
    const bf16_t* __restrict__ Vtg, bf16_t* __restrict__ Og)
{
  // [0,65536)B: buf0 {K [256][64], V [64][256]}; [65536,131072)B: buf1;
  // epilogue alias: PART[qh][ks][64q][64d] f32 = 128 KB; PL at [131072,133120)B
  __shared__ __align__(16) bf16_t smem[66560];   // 133,120 B

  const int tid  = threadIdx.x;
  const int lane = tid & 63;
  const int w    = tid >> 6;               // 0..7
  const int qh   = w >> 2;                 // q 64-half of the 128-row tile
  const int ks   = w & 3;                  // k 64-quarter of the 256-k window
  const int quad = lane >> 4;
  const int l15  = lane & 15;
  const int l7   = lane & 7;

  const int id = blockIdx.x;               // 0..255
  const int bh = 2 * (id & 7) + ((id >> 3) & 1);   // 2 bh per XCD (L2 reuse)
  const int x  = id >> 4;                  // 0..15
  const int qtA = 31 - x, qtB = x;
  const size_t bh_off = (size_t)bh * 262144;
  const int b = bh >> 3, h = bh & 7;

  bf16x8 aq0[4], aq1[4];                   // Q frags: 4 q-blocks of 16 rows
  auto loadQ = [&](int qt) {
    #pragma unroll
    for (int qb = 0; qb < 4; ++qb) {
      const bf16_t* Qp = Qg + bh_off +
                         (size_t)(qt * 128 + qh * 64 + qb * 16 + l15) * 64;
      aq0[qb] = *(const bf16x8*)&Qp[quad * 8];
      aq1[qb] = *(const bf16x8*)&Qp[32 + quad * 8];
    }
  };

  bf16x8 ones;
  #pragma unroll
  for (int i = 0; i < 8; ++i) ones[i] = (bf16_t)1.0f;

  floatx4 acc_o[4][4], acc_l[4];
  auto zacc = [&]() {
    #pragma unroll
    for (int qb = 0; qb < 4; ++qb) {
      #pragma unroll
      for (int dt = 0; dt < 4; ++dt) acc_o[qb][dt] = (floatx4){0.f, 0.f, 0.f, 0.f};
      acc_l[qb] = (floatx4){0.f, 0.f, 0.f, 0.f};
    }
  };

  // stage one 256-k window: K 32 KB [256][64] + V 32 KB [64][256]
  auto stage = [&](int buf, int j) {
    const bf16_t* Kp = Kgl + bh_off + (size_t)j * 16384;
    const bf16_t* Vp = Vtg + bh_off + (size_t)j * 256;
    const int base = buf * 32768;
    #pragma unroll
    for (int i = 0; i < 4; ++i) {
      int c = tid + 512 * i;               // 0..2047
      int row = c >> 3, p = c & 7;
      GLDS16(&Kp[(size_t)row * 64 + ((p ^ (row & 7)) << 3)], &smem[base + c * 8]);
    }
    #pragma unroll
    for (int i = 0; i < 4; ++i) {
      int c = tid + 512 * i;
      int row = c >> 5, p = c & 31;
      GLDS16(&Vp[(size_t)row * 4096 + ((p ^ (row & 15)) << 3)],
             &smem[base + 16384 + c * 8]);
    }
  };

  // epilogue: merge 4 k-quarter partials per q-half, normalize, store 128x64
  auto epi = [&](int qt) {
    __syncthreads();                       // compute done; alias staging
    {
      float* Pq = (float*)&smem[0] + qh * 16384 + ks * 4096;   // [64q][64d]
      float* PL = (float*)&smem[65536];                        // [qh][ks][64]
      #pragma unroll
      for (int qb = 0; qb < 4; ++qb) {
        int q = qb * 16 + l15;
        #pragma unroll
        for (int dt = 0; dt < 4; ++dt)
          *(floatx4*)&Pq[q * 64 + (((dt * 4 + quad) ^ l15) << 2)] = acc_o[qb][dt];
        if (quad == 0) PL[qh * 256 + ks * 64 + q] = acc_l[qb][0];
      }
    }
    __syncthreads();
    #pragma unroll
    for (int i = 0; i < 2; ++i) {          // 1024 cells: (qh, q, 8d-chunk)
      int a = tid + 512 * i;
      int qh_e = a >> 9, rem = a & 511;
      int q = rem >> 3, c8 = rem & 7;
      const float* Pq = (const float*)&smem[0] + qh_e * 16384;
      const float* PL = (const float*)&smem[65536] + qh_e * 256;
      float s0[8] = {0.f, 0.f, 0.f, 0.f, 0.f, 0.f, 0.f, 0.f};
      float suml = 0.f;
      #pragma unroll
      for (int k2 = 0; k2 < 4; ++k2) {
        const float* Pk = Pq + k2 * 4096 + q * 64;
        floatx4 u0 = *(const floatx4*)&Pk[((c8 * 2)     ^ (q & 15)) << 2];
        floatx4 u1 = *(const floatx4*)&Pk[((c8 * 2 + 1) ^ (q & 15)) << 2];
        #pragma unroll
        for (int r = 0; r < 4; ++r) { s0[r] += u0[r]; s0[4 + r] += u1[r]; }
        suml += PL[k2 * 64 + q];
      }
      float rl = 1.0f / suml;
      bf16x8 o;
      #pragma unroll
      for (int e = 0; e < 8; ++e) o[e] = (bf16_t)(s0[e] * rl);
      int row = qt * 128 + qh_e * 64 + q;
      *(bf16x8*)&Og[((size_t)b * 4096 + row) * 512 + h * 64 + c8 * 8] = o;
    }
  };

  const floatx4 z4 = (floatx4){0.f, 0.f, 0.f, 0.f};
  for (int ph = 0; ph < 2; ++ph) {
    const int qt = ph ? qtB : qtA;
    if (ph) __syncthreads();               // PART reads done before restage
    zacc();
    loadQ(qt);
    stage(0, 0);
    const int N = (2 * qt + 5) >> 2;       // ceil((2qt+2)/4): 1..16
    const int lim = 2 * qt + qh;           // wave's causal k64 limit
    for (int j = 0; j < N; ++j) {
      const int cur = j & 1;
      __syncthreads();                     // cur's loads landed during prev iter
      if (j + 1 < N) stage(cur ^ 1, j + 1);
      const int kk = 4 * j + ks;           // wave's k64 index
      if (kk <= lim) {                     // wave-uniform causal activity
        const bf16_t* Kc = &smem[cur * 32768 + ks * 4096];
        const bf16_t* Vc = &smem[cur * 32768 + 16384];
        // ---- S^T = K Q^T : 64 k-rows x 64 q-cols per wave ----
        floatx4 s[4][4];                   // [qb][nt]
        #pragma unroll
        for (int nt = 0; nt < 4; ++nt) {
          bf16x8 bk = *(const bf16x8*)&Kc[(nt * 16 + l15) * 64 +
                                          ((quad ^ l7) << 3)];
          s[0][nt] = mfma16(bk, aq0[0], z4);
          s[1][nt] = mfma16(bk, aq0[1], z4);
          s[2][nt] = mfma16(bk, aq0[2], z4);
          s[3][nt] = mfma16(bk, aq0[3], z4);
        }
        #pragma unroll
        for (int nt = 0; nt < 4; ++nt) {
          bf16x8 bk = *(const bf16x8*)&Kc[(nt * 16 + l15) * 64 +
                                          (((4 + quad) ^ l7) << 3)];
          #pragma unroll
          for (int qb = 0; qb < 4; ++qb)
            s[qb][nt] = mfma16(bk, aq1[qb], s[qb][nt]);
        }
        // ---- no-max softmax, log2 domain ----
        if (kk == lim) {                   // diagonal 64-block: mask k > q
          #pragma unroll
          for (int qb = 0; qb < 4; ++qb)
            #pragma unroll
            for (int nt = 0; nt < 4; ++nt)
              #pragma unroll
              for (int r = 0; r < 4; ++r)
                if (nt * 16 + quad * 4 + r > qb * 16 + l15)
                  s[qb][nt][r] = -3.0e38f;
        }
        #pragma unroll
        for (int qb = 0; qb < 4; ++qb)
          #pragma unroll
          for (int nt = 0; nt < 4; ++nt)
            #pragma unroll
            for (int r = 0; r < 4; ++r)
              s[qb][nt][r] = __builtin_amdgcn_exp2f(s[qb][nt][r]);
        // ---- PV: O^T += V^T P^T ; l += 1^T P^T (V frags shared by 4 qb) ----
        #pragma unroll
        for (int kc = 0; kc < 2; ++kc) {
          bf16x8 pb[4];
          #pragma unroll
          for (int qb = 0; qb < 4; ++qb)
            #pragma unroll
            for (int r = 0; r < 4; ++r) {
              pb[qb][r]     = (bf16_t)s[qb][kc * 2][r];
              pb[qb][r + 4] = (bf16_t)s[qb][kc * 2 + 1][r];
            }
          #pragma unroll
          for (int qb = 0; qb < 4; ++qb)
            acc_l[qb] = mfma16(ones, pb[qb], acc_l[qb]);
          #pragma unroll
          for (int dt = 0; dt < 4; ++dt) {
            bf16x8 av = *(const bf16x8*)&Vc[(dt * 16 + l15) * 256 +
                           ((((ks * 2 + kc) * 4 + quad) ^ l15) << 3)];
            #pragma unroll
            for (int qb = 0; qb < 4; ++qb)
              acc_o[qb][dt] = mfma16(av, pb[qb], acc_o[qb][dt]);
          }
        }
      }
    }
    epi(qt);
  }
}

// ---------------- launcher ----------------
extern "C" void kernel_launch(void* const* d_in, const int* in_sizes, int n_in,
                              void* d_out, int out_size, void* d_ws, size_t ws_size,
                              hipStream_t stream) {
  const float* x    = (const float*)d_in[0];   // (2,4096,512)
  const float* wqkv = (const float*)d_in[1];   // (1536,512)
  const float* wo   = (const float*)d_in[2];   // (512,512)
  float* out = (float*)d_out;                  // (2,4096,512) fp32

  char* ws = (char*)d_ws;
  bf16_t* xb    = (bf16_t*)(ws);                 //  8 MB (reused as Ob after gemm1)
  bf16_t* wqkvb = (bf16_t*)(ws + 8388608);       //  1.5 MB
  bf16_t* wob   = (bf16_t*)(ws + 9961472);       //  0.5 MB
  bf16_t* Qb    = (bf16_t*)(ws + 10485760);      //  8 MB  [bh][t][64], pre-scaled
  bf16_t* Kb    = (bf16_t*)(ws + 18874368);      //  8 MB  [bh][t][64]
  bf16_t* Vtb   = (bf16_t*)(ws + 27262976);      //  8 MB  [bh][64][t'] k-interleaved
  bf16_t* Ob    = xb;                            //  alias: gemm1 done with xb
  // total 35,651,584 bytes

  cvt_all_kernel<<<5120, 256, 0, stream>>>(x, wqkv, wo, xb, wqkvb, wob);

  gemm_qkv<<<dim3(64, 12), 256, 0, stream>>>(xb, wqkvb, Qb, Kb, Vtb);
  attn_kernel<<<dim3(256), 512, 0, stream>>>(Qb, Kb, Vtb, Ob);
  gemm_out<<<dim3(128, 4), 256, 0, stream>>>(Ob, wob, out);
}

// Round 9
// 148.075 us; speedup vs baseline: 1.0391x; 1.0391x over previous
//
#include <hip/hip_runtime.h>
#include <hip/hip_bf16.h>

typedef __bf16 bf16_t;
typedef __bf16 bf16x8 __attribute__((ext_vector_type(8)));
typedef __bf16 bf16x4 __attribute__((ext_vector_type(4)));
typedef float  floatx4 __attribute__((ext_vector_type(4)));

static __device__ __forceinline__ floatx4 mfma16(bf16x8 a, bf16x8 b, floatx4 c) {
  return __builtin_amdgcn_mfma_f32_16x16x32_bf16(a, b, c, 0, 0, 0);
}

// async global->LDS, 16B per lane; LDS dest = wave-uniform base + lane*16.
typedef __attribute__((address_space(3))) void lds_vp;
typedef __attribute__((address_space(1))) void glb_vp;
#define GLDS16(g, l) \
  __builtin_amdgcn_global_load_lds((glb_vp*)(g), (lds_vp*)(l), 16, 0, 0)

// ---------------- fused fp32 -> bf16 convert (x, W_QKV, W_O) ----------------
__global__ void cvt_all_kernel(const float* __restrict__ x,
                               const float* __restrict__ wqkv,
                               const float* __restrict__ wo,
                               bf16_t* __restrict__ xb,
                               bf16_t* __restrict__ wqkvb,
                               bf16_t* __restrict__ wob) {
  int i = blockIdx.x * blockDim.x + threadIdx.x;     // 0..1310719 float4s
  const float4* src; bf16x4* dst; int off;
  if (i < 1048576)      { src = (const float4*)x;    dst = (bf16x4*)xb;    off = i; }
  else if (i < 1245184) { src = (const float4*)wqkv; dst = (bf16x4*)wqkvb; off = i - 1048576; }
  else                  { src = (const float4*)wo;   dst = (bf16x4*)wob;   off = i - 1245184; }
  float4 v = src[off];
  bf16x4 o;
  o[0] = (bf16_t)v.x; o[1] = (bf16_t)v.y; o[2] = (bf16_t)v.z; o[3] = (bf16_t)v.w;
  dst[off] = o;
}

// ---------------- QKV GEMM: C(M,N) = A(M,K) * B(N,K)^T ----------------
// Epilogues write attn-ready layouts:
//   Q  [bh][t][64] pre-scaled by 0.125*log2e (softmax in log2 domain)
//   Kf [bh][t>>4][d>>5][lane][8]  MFMA-A-fragment-linear: lane=((d&31)>>3)*16+(t&15)
//   Vf [bh][t'>>5][d>>4][lane][8] V^T fragment-linear:    lane=((t'>>3)&3)*16+(d&15)
// so attn reads every fragment as ONE coalesced global_load_dwordx4 (no LDS).
__global__ __launch_bounds__(256) void gemm_qkv(
    const bf16_t* __restrict__ A, const bf16_t* __restrict__ B,
    bf16_t* __restrict__ Qo, bf16_t* __restrict__ Ko, bf16_t* __restrict__ Vto)
{
  __shared__ __align__(16) bf16_t As[2][128 * 64];
  __shared__ __align__(16) bf16_t Bs[2][128 * 64];
  const int tid  = threadIdx.x;
  const int lane = tid & 63;
  const int w    = tid >> 6;
  const int quad = lane >> 4;
  const int l15  = lane & 15;
  const int l7   = lane & 7;
  const int wm   = w & 1;
  const int wn   = w >> 1;
  const int K    = 512;

  floatx4 acc[4][4];
  #pragma unroll
  for (int i = 0; i < 4; ++i)
    #pragma unroll
    for (int j = 0; j < 4; ++j)
      acc[i][j] = (floatx4){0.f, 0.f, 0.f, 0.f};

  const bf16_t* Ab = A + (size_t)blockIdx.x * 128 * K;
  const bf16_t* Bb = B + (size_t)blockIdx.y * 128 * K;

  auto stage = [&](int buf, int k0) {
    #pragma unroll
    for (int i = 0; i < 4; ++i) {
      int c = tid + 256 * i;
      int row = c >> 3, colc = c & 7;
      int gofs = ((colc ^ (row & 7)) << 3);
      GLDS16(&Ab[(size_t)row * K + k0 + gofs], &As[buf][c * 8]);
      GLDS16(&Bb[(size_t)row * K + k0 + gofs], &Bs[buf][c * 8]);
    }
  };

  stage(0, 0);
  for (int it = 0; it < 8; ++it) {
    const int cur = it & 1;
    __syncthreads();
    if (it + 1 < 8) stage(cur ^ 1, (it + 1) << 6);
    #pragma unroll
    for (int ks = 0; ks < 2; ++ks) {
      bf16x8 af[4], bfr[4];
      #pragma unroll
      for (int t = 0; t < 4; ++t) {
        af[t]  = *(const bf16x8*)&As[cur][(wm * 64 + t * 16 + l15) * 64 +
                                         (((ks * 4 + quad) ^ l7) << 3)];
        bfr[t] = *(const bf16x8*)&Bs[cur][(wn * 64 + t * 16 + l15) * 64 +
                                         (((ks * 4 + quad) ^ l7) << 3)];
      }
      #pragma unroll
      for (int mt = 0; mt < 4; ++mt)
        #pragma unroll
        for (int nt = 0; nt < 4; ++nt)
          acc[mt][nt] = mfma16(af[mt], bfr[nt], acc[mt][nt]);
    }
  }

  if (blockIdx.y < 8) {
    // ---- Q / K scatter epilogue ----
    #pragma unroll
    for (int mt = 0; mt < 4; ++mt) {
      #pragma unroll
      for (int nt = 0; nt < 4; ++nt) {
        #pragma unroll
        for (int r = 0; r < 4; ++r) {
          int m = blockIdx.x * 128 + wm * 64 + mt * 16 + quad * 4 + r;
          int n = blockIdx.y * 128 + wn * 64 + nt * 16 + l15;
          float v = acc[mt][nt][r];
          int b = m >> 12, t = m & 4095;
          int h = (n >> 6) & 7, d = n & 63;
          size_t bh = (size_t)(b * 8 + h);
          if (n < 512)   // fold 1/sqrt(64) * log2(e) -> softmax in log2 domain
            Qo[bh * 262144 + (size_t)t * 64 + d] = (bf16_t)(v * 0.18033688f);
          else           // K fragment-linear
            Ko[bh * 262144 +
               (size_t)((((t >> 4) * 2 + (d >> 5)) * 512) +
                        ((((d & 31) >> 3) * 16 + (t & 15)) * 8) + (d & 7))] =
                (bf16_t)v;
        }
      }
    }
  } else {
    // ---- V epilogue: transpose through LDS (As region, 32 KB) ----
    __syncthreads();                       // everyone done reading As/Bs
    bf16_t* L = &As[0][0];                 // [n_local][m swizzled] 128x128
    #pragma unroll
    for (int mt = 0; mt < 4; ++mt)
      #pragma unroll
      for (int nt = 0; nt < 4; ++nt) {
        int n_l = wn * 64 + nt * 16 + l15;
        int mc  = wm * 8 + mt * 2 + (quad >> 1);     // m-chunk of 8
        bf16x4 v4;
        #pragma unroll
        for (int r = 0; r < 4; ++r) v4[r] = (bf16_t)acc[mt][nt][r];
        *(bf16x4*)&L[n_l * 128 + ((mc ^ (n_l & 15)) << 3) + (quad & 1) * 4] = v4;
      }
    __syncthreads();
    const int t0 = (blockIdx.x & 31) * 128;
    const int b  = blockIdx.x >> 5;
    #pragma unroll
    for (int i = 0; i < 8; ++i) {
      int c = tid + 256 * i;               // 0..2047: n_l = c>>4, tc = c&15
      int n_l = c >> 4, tc = c & 15;
      int h = ((blockIdx.y - 8) << 1) | (n_l >> 6);
      int d = n_l & 63;
      size_t bh = (size_t)(b * 8 + h);
      int base0 = (tc >> 2) * 32 + (tc & 3) * 4;
      bf16x4 lo = *(const bf16x4*)&L[n_l * 128 +
                     (((base0 >> 3) ^ (n_l & 15)) << 3) + (base0 & 7)];
      bf16x4 hi = *(const bf16x4*)&L[n_l * 128 +
                     ((((base0 + 16) >> 3) ^ (n_l & 15)) << 3) + (base0 & 7)];
      bf16x8 o;
      #pragma unroll
      for (int e = 0; e < 4; ++e) { o[e] = lo[e]; o[e + 4] = hi[e]; }
      int T = t0 + tc * 8;                 // t' base of this 8-chunk
      *(bf16x8*)&Vto[bh * 262144 +
                     (size_t)((((T >> 5) * 4 + (d >> 4)) * 512) +
                              ((((T >> 3) & 3) * 16 + (d & 15)) * 8))] = o;
    }
  }
}

// ---------------- output GEMM: out(8192,512) = Ob(8192,512) * Wo(512,512)^T ----
__global__ __launch_bounds__(256) void gemm_out(
    const bf16_t* __restrict__ A, const bf16_t* __restrict__ B,
    float* __restrict__ Cf)
{
  __shared__ __align__(16) bf16_t As[2][64 * 64];
  __shared__ __align__(16) bf16_t Bs[2][128 * 64];
  const int tid  = threadIdx.x;
  const int lane = tid & 63;
  const int w    = tid >> 6;               // 0..3, owns n-range w*32..+32
  const int quad = lane >> 4;
  const int l15  = lane & 15;
  const int l7   = lane & 7;

  floatx4 acc[4][2];
  #pragma unroll
  for (int i = 0; i < 4; ++i)
    #pragma unroll
    for (int j = 0; j < 2; ++j)
      acc[i][j] = (floatx4){0.f, 0.f, 0.f, 0.f};

  const bf16_t* Ab = A + (size_t)blockIdx.x * 64 * 512;
  const bf16_t* Bb = B + (size_t)blockIdx.y * 128 * 512;

  auto stage = [&](int buf, int k0) {
    #pragma unroll
    for (int i = 0; i < 2; ++i) {          // A: 512 chunks
      int c = tid + 256 * i;
      int row = c >> 3, colc = c & 7;
      GLDS16(&Ab[(size_t)row * 512 + k0 + ((colc ^ (row & 7)) << 3)],
             &As[buf][c * 8]);
    }
    #pragma unroll
    for (int i = 0; i < 4; ++i) {          // B: 1024 chunks
      int c = tid + 256 * i;
      int row = c >> 3, colc = c & 7;
      GLDS16(&Bb[(size_t)row * 512 + k0 + ((colc ^ (row & 7)) << 3)],
             &Bs[buf][c * 8]);
    }
  };

  stage(0, 0);
  for (int it = 0; it < 8; ++it) {
    const int cur = it & 1;
    __syncthreads();
    if (it + 1 < 8) stage(cur ^ 1, (it + 1) << 6);
    #pragma unroll
    for (int ks = 0; ks < 2; ++ks) {
      bf16x8 af[4], bfr[2];
      #pragma unroll
      for (int t = 0; t < 4; ++t)
        af[t]  = *(const bf16x8*)&As[cur][(t * 16 + l15) * 64 +
                                         (((ks * 4 + quad) ^ l7) << 3)];
      #pragma unroll
      for (int t = 0; t < 2; ++t)
        bfr[t] = *(const bf16x8*)&Bs[cur][(w * 32 + t * 16 + l15) * 64 +
                                         (((ks * 4 + quad) ^ l7) << 3)];
      #pragma unroll
      for (int mt = 0; mt < 4; ++mt)
        #pragma unroll
        for (int nt = 0; nt < 2; ++nt)
          acc[mt][nt] = mfma16(af[mt], bfr[nt], acc[mt][nt]);
    }
  }

  #pragma unroll
  for (int mt = 0; mt < 4; ++mt)
    #pragma unroll
    for (int nt = 0; nt < 2; ++nt)
      #pragma unroll
      for (int r = 0; r < 4; ++r) {
        int m = blockIdx.x * 64 + mt * 16 + quad * 4 + r;
        int n = blockIdx.y * 128 + w * 32 + nt * 16 + l15;
        Cf[(size_t)m * 512 + n] = acc[mt][nt][r];
      }
}

// ---- causal flash attention: register-direct, no LDS staging, no barriers ----
// 256 blocks x 512 threads (8 waves), 1 block/CU. Waves = {tile(qtA/qtB)} x
// {q-half} x {k-half}, each 64q x 64k per k64-step (R3's proven 72-MFMA body).
// K/V are read DIRECTLY from global in fragment-linear layout (Kf/Vf, written
// by gemm_qkv) as coalesced dwordx4 loads: K/V are L2-resident (1 MB/bh, 2 bh
// per XCD), so LDS staging was pure overhead and its barriers phase-locked all
// waves (MfmaUtil==VALUBusy==LDS ~30% serialized across R3/R7/R8). With zero
// main-loop barriers, waves drift: exp2 (trans pipe) of one wave overlaps MFMA
// of its SIMD-mate; L2 latency hides under the MFMA chain; av loads issue
// under exp2. One __syncthreads before the LDS merge epilogue (kh partials).
// No-max log2-domain softmax (scores bounded, fp32-safe).
__global__ __launch_bounds__(512, 1) void attn_kernel(
    const bf16_t* __restrict__ Qg, const bf16_t* __restrict__ Kf,
    const bf16_t* __restrict__ Vf, bf16_t* __restrict__ Og)
{
  __shared__ __align__(16) bf16_t smem[49664];   // epilogue only: 99,328 B

  const int tid  = threadIdx.x;
  const int lane = tid & 63;
  const int w    = tid >> 6;               // 0..7
  const int tile = w >> 2;                 // 0 = qtA, 1 = qtB
  const int qh   = (w >> 1) & 1;           // 64-q half of the 128-row tile
  const int kh   = w & 1;                  // k64 parity this wave owns
  const int quad = lane >> 4;
  const int l15  = lane & 15;

  const int id = blockIdx.x;               // 0..255
  const int bh = 2 * (id & 7) + ((id >> 3) & 1);   // 2 bh per XCD (L2 reuse)
  const int x  = id >> 4;                  // 0..15
  const int qtA = 31 - x, qtB = x;
  const int qt  = tile ? qtB : qtA;
  const int q64 = 2 * qt + qh;             // wave's 64-row q-block index
  const size_t bh_off = (size_t)bh * 262144;
  const int b = bh >> 3, h = bh & 7;

  // Q fragments (pre-scaled by 0.125*log2e): 4 q-blocks of 16 rows
  const int qbase = qt * 128 + qh * 64;
  bf16x8 aq0[4], aq1[4];
  #pragma unroll
  for (int qb = 0; qb < 4; ++qb) {
    const bf16_t* Qp = Qg + bh_off + (size_t)(qbase + qb * 16 + l15) * 64;
    aq0[qb] = *(const bf16x8*)&Qp[quad * 8];
    aq1[qb] = *(const bf16x8*)&Qp[32 + quad * 8];
  }
  bf16x8 ones;
  #pragma unroll
  for (int i = 0; i < 8; ++i) ones[i] = (bf16_t)1.0f;

  floatx4 acc_o[4][4], acc_l[4];
  #pragma unroll
  for (int qb = 0; qb < 4; ++qb) {
    #pragma unroll
    for (int dt = 0; dt < 4; ++dt) acc_o[qb][dt] = (floatx4){0.f, 0.f, 0.f, 0.f};
    acc_l[qb] = (floatx4){0.f, 0.f, 0.f, 0.f};
  }

  const bf16_t* Kb_ = Kf + bh_off;
  const bf16_t* Vb_ = Vf + bh_off;
  const floatx4 z4 = (floatx4){0.f, 0.f, 0.f, 0.f};

  for (int k64 = kh; k64 <= q64; k64 += 2) {
    const bf16_t* Kp = Kb_ + (size_t)k64 * 4096;   // 8 K-frags of 512 elems
    const bf16_t* Vp = Vb_ + (size_t)k64 * 4096;   // 8 V-frags of 512 elems
    // ---- K fragment loads: coalesced, L2-hot ----
    bf16x8 bk0[4], bk1[4];
    #pragma unroll
    for (int nt = 0; nt < 4; ++nt) {
      bk0[nt] = *(const bf16x8*)&Kp[(nt * 2 + 0) * 512 + lane * 8];
      bk1[nt] = *(const bf16x8*)&Kp[(nt * 2 + 1) * 512 + lane * 8];
    }
    // ---- S^T = K Q^T : 64 k-rows x 64 q-cols ----
    floatx4 s[4][4];                       // [qb][nt]
    #pragma unroll
    for (int nt = 0; nt < 4; ++nt) {
      s[0][nt] = mfma16(bk0[nt], aq0[0], z4);
      s[1][nt] = mfma16(bk0[nt], aq0[1], z4);
      s[2][nt] = mfma16(bk0[nt], aq0[2], z4);
      s[3][nt] = mfma16(bk0[nt], aq0[3], z4);
    }
    #pragma unroll
    for (int nt = 0; nt < 4; ++nt)
      #pragma unroll
      for (int qb = 0; qb < 4; ++qb)
        s[qb][nt] = mfma16(bk1[nt], aq1[qb], s[qb][nt]);
    // ---- V fragment loads (latency hides under exp2) ----
    bf16x8 av[2][4];
    #pragma unroll
    for (int kc = 0; kc < 2; ++kc)
      #pragma unroll
      for (int dt = 0; dt < 4; ++dt)
        av[kc][dt] = *(const bf16x8*)&Vp[(kc * 4 + dt) * 512 + lane * 8];
    // ---- no-max softmax, log2 domain ----
    if (k64 == q64) {                      // diagonal 64-block: mask k > q
      #pragma unroll
      for (int qb = 0; qb < 4; ++qb)
        #pragma unroll
        for (int nt = 0; nt < 4; ++nt)
          #pragma unroll
          for (int r = 0; r < 4; ++r)
            if (nt * 16 + quad * 4 + r > qb * 16 + l15)
              s[qb][nt][r] = -3.0e38f;
    }
    #pragma unroll
    for (int qb = 0; qb < 4; ++qb)
      #pragma unroll
      for (int nt = 0; nt < 4; ++nt)
        #pragma unroll
        for (int r = 0; r < 4; ++r)
          s[qb][nt][r] = __builtin_amdgcn_exp2f(s[qb][nt][r]);
    // ---- PV: O^T += V^T P^T ; l += 1^T P^T ----
    #pragma unroll
    for (int kc = 0; kc < 2; ++kc) {
      bf16x8 pb[4];
      #pragma unroll
      for (int qb = 0; qb < 4; ++qb)
        #pragma unroll
        for (int r = 0; r < 4; ++r) {
          pb[qb][r]     = (bf16_t)s[qb][kc * 2][r];
          pb[qb][r + 4] = (bf16_t)s[qb][kc * 2 + 1][r];
        }
      #pragma unroll
      for (int qb = 0; qb < 4; ++qb)
        acc_l[qb] = mfma16(ones, pb[qb], acc_l[qb]);
      #pragma unroll
      for (int dt = 0; dt < 4; ++dt)
        #pragma unroll
        for (int qb = 0; qb < 4; ++qb)
          acc_o[qb][dt] = mfma16(av[kc][dt], pb[qb], acc_o[qb][dt]);
    }
  }

  // ---- epilogue: merge k-half partials (f32, LDS), transpose, store ----
  __syncthreads();                         // all waves done computing
  float*  PART = (float*)smem;             // 4 pairs x 4160 f32 (O^T + l)
  bf16_t* OUT  = smem + 33280;             // 4 pairs x 4096 bf16 (byte 66560)
  const int p = w >> 1;                    // pair = tile*2 + qh
  float* P = PART + p * 4160;

  if (kh == 1) {                           // write partials
    #pragma unroll
    for (int qb = 0; qb < 4; ++qb) {
      #pragma unroll
      for (int dt = 0; dt < 4; ++dt) {
        int chunk = (dt * 4 + quad) ^ l15;
        *(floatx4*)&P[(qb * 16 + l15) * 64 + chunk * 4] = acc_o[qb][dt];
      }
      if (quad == 0) P[4096 + qb * 16 + l15] = acc_l[qb][0];
    }
  }
  __syncthreads();
  if (kh == 0) {                           // merge + normalize + transpose-store
    bf16_t* Ot = OUT + p * 4096;
    #pragma unroll
    for (int qb = 0; qb < 4; ++qb) {
      const int t_own = qb * 16 + l15;
      float rl = 1.0f / (acc_l[qb][0] + P[4096 + t_own]);
      #pragma unroll
      for (int dt = 0; dt < 4; ++dt) {
        int chunk = (dt * 4 + quad) ^ l15;
        floatx4 pp = *(const floatx4*)&P[t_own * 64 + chunk * 4];
        bf16x4 o4;
        #pragma unroll
        for (int r = 0; r < 4; ++r)
          o4[r] = (bf16_t)((acc_o[qb][dt][r] + pp[r]) * rl);
        *(bf16x4*)&Ot[t_own * 64 +
                      (((dt * 2 + (quad >> 1)) ^ (t_own & 7)) << 3) +
                      (quad & 1) * 4] = o4;
      }
    }
  }
  __syncthreads();
  {                                        // coalesced global write, 2 waves/pair
    bf16_t* Ot = OUT + p * 4096;
    const int gtid = ((w & 1) << 6) | lane;          // 0..127
    #pragma unroll
    for (int i = 0; i < 4; ++i) {
      int cc = gtid + 128 * i;             // 0..511 : 64 t-rows x 8 chunks
      int t = cc >> 3, c = cc & 7;
      bf16x8 o8 = *(const bf16x8*)&Ot[t * 64 + ((c ^ (t & 7)) << 3)];
      int trow = qbase + t;
      *(bf16x8*)&Og[((size_t)b * 4096 + trow) * 512 + h * 64 + c * 8] = o8;
    }
  }
}

// ---------------- launcher ----------------
extern "C" void kernel_launch(void* const* d_in, const int* in_sizes, int n_in,
                              void* d_out, int out_size, void* d_ws, size_t ws_size,
                              hipStream_t stream) {
  const float* x    = (const float*)d_in[0];   // (2,4096,512)
  const float* wqkv = (const float*)d_in[1];   // (1536,512)
  const float* wo   = (const float*)d_in[2];   // (512,512)
  float* out = (float*)d_out;                  // (2,4096,512) fp32

  char* ws = (char*)d_ws;
  bf16_t* xb    = (bf16_t*)(ws);                 //  8 MB (reused as Ob after gemm1)
  bf16_t* wqkvb = (bf16_t*)(ws + 8388608);       //  1.5 MB
  bf16_t* wob   = (bf16_t*)(ws + 9961472);       //  0.5 MB
  bf16_t* Qb    = (bf16_t*)(ws + 10485760);      //  8 MB  [bh][t][64], pre-scaled
  bf16_t* Kfb   = (bf16_t*)(ws + 18874368);      //  8 MB  K fragment-linear
  bf16_t* Vfb   = (bf16_t*)(ws + 27262976);      //  8 MB  V^T fragment-linear
  bf16_t* Ob    = xb;                            //  alias: gemm1 done with xb
  // total 35,651,584 bytes

  cvt_all_kernel<<<5120, 256, 0, stream>>>(x, wqkv, wo, xb, wqkvb, wob);

  gemm_qkv<<<dim3(64, 12), 256, 0, stream>>>(xb, wqkvb, Qb, Kfb, Vfb);
  attn_kernel<<<dim3(256), 512, 0, stream>>>(Qb, Kfb, Vfb, Ob);
  gemm_out<<<dim3(128, 4), 256, 0, stream>>>(Ob, wob, out);
}

// Round 10
// 144.771 us; speedup vs baseline: 1.0628x; 1.0228x over previous
//
#include <hip/hip_runtime.h>
#include <hip/hip_bf16.h>

typedef __bf16 bf16_t;
typedef __bf16 bf16x8 __attribute__((ext_vector_type(8)));
typedef __bf16 bf16x4 __attribute__((ext_vector_type(4)));
typedef float  floatx4 __attribute__((ext_vector_type(4)));

static __device__ __forceinline__ floatx4 mfma16(bf16x8 a, bf16x8 b, floatx4 c) {
  return __builtin_amdgcn_mfma_f32_16x16x32_bf16(a, b, c, 0, 0, 0);
}

// async global->LDS, 16B per lane; LDS dest = wave-uniform base + lane*16.
typedef __attribute__((address_space(3))) void lds_vp;
typedef __attribute__((address_space(1))) void glb_vp;
#define GLDS16(g, l) \
  __builtin_amdgcn_global_load_lds((glb_vp*)(g), (lds_vp*)(l), 16, 0, 0)

// ---------------- fused fp32 -> bf16 convert (x, W_QKV, W_O) ----------------
__global__ void cvt_all_kernel(const float* __restrict__ x,
                               const float* __restrict__ wqkv,
                               const float* __restrict__ wo,
                               bf16_t* __restrict__ xb,
                               bf16_t* __restrict__ wqkvb,
                               bf16_t* __restrict__ wob) {
  int i = blockIdx.x * blockDim.x + threadIdx.x;     // 0..1310719 float4s
  const float4* src; bf16x4* dst; int off;
  if (i < 1048576)      { src = (const float4*)x;    dst = (bf16x4*)xb;    off = i; }
  else if (i < 1245184) { src = (const float4*)wqkv; dst = (bf16x4*)wqkvb; off = i - 1048576; }
  else                  { src = (const float4*)wo;   dst = (bf16x4*)wob;   off = i - 1245184; }
  float4 v = src[off];
  bf16x4 o;
  o[0] = (bf16_t)v.x; o[1] = (bf16_t)v.y; o[2] = (bf16_t)v.z; o[3] = (bf16_t)v.w;
  dst[off] = o;
}

// ---------------- QKV GEMM: C(M,N) = A(M,K) * B(N,K)^T ----------------
// Epilogues write attn-ready layouts:
//   Q  [bh][t][64] pre-scaled by 0.125*log2e (softmax in log2 domain)
//   Kf [bh][t>>4][d>>5][lane][8]  MFMA-A-fragment-linear: lane=((d&31)>>3)*16+(t&15)
//   Vf [bh][t'>>5][d>>4][lane][8] V^T fragment-linear:    lane=((t'>>3)&3)*16+(d&15)
// so attn reads every fragment as ONE coalesced global_load_dwordx4 (no LDS).
__global__ __launch_bounds__(256) void gemm_qkv(
    const bf16_t* __restrict__ A, const bf16_t* __restrict__ B,
    bf16_t* __restrict__ Qo, bf16_t* __restrict__ Ko, bf16_t* __restrict__ Vto)
{
  __shared__ __align__(16) bf16_t As[2][128 * 64];
  __shared__ __align__(16) bf16_t Bs[2][128 * 64];
  const int tid  = threadIdx.x;
  const int lane = tid & 63;
  const int w    = tid >> 6;
  const int quad = lane >> 4;
  const int l15  = lane & 15;
  const int l7   = lane & 7;
  const int wm   = w & 1;
  const int wn   = w >> 1;
  const int K    = 512;

  floatx4 acc[4][4];
  #pragma unroll
  for (int i = 0; i < 4; ++i)
    #pragma unroll
    for (int j = 0; j < 4; ++j)
      acc[i][j] = (floatx4){0.f, 0.f, 0.f, 0.f};

  const bf16_t* Ab = A + (size_t)blockIdx.x * 128 * K;
  const bf16_t* Bb = B + (size_t)blockIdx.y * 128 * K;

  auto stage = [&](int buf, int k0) {
    #pragma unroll
    for (int i = 0; i < 4; ++i) {
      int c = tid + 256 * i;
      int row = c >> 3, colc = c & 7;
      int gofs = ((colc ^ (row & 7)) << 3);
      GLDS16(&Ab[(size_t)row * K + k0 + gofs], &As[buf][c * 8]);
      GLDS16(&Bb[(size_t)row * K + k0 + gofs], &Bs[buf][c * 8]);
    }
  };

  stage(0, 0);
  for (int it = 0; it < 8; ++it) {
    const int cur = it & 1;
    __syncthreads();
    if (it + 1 < 8) stage(cur ^ 1, (it + 1) << 6);
    #pragma unroll
    for (int ks = 0; ks < 2; ++ks) {
      bf16x8 af[4], bfr[4];
      #pragma unroll
      for (int t = 0; t < 4; ++t) {
        af[t]  = *(const bf16x8*)&As[cur][(wm * 64 + t * 16 + l15) * 64 +
                                         (((ks * 4 + quad) ^ l7) << 3)];
        bfr[t] = *(const bf16x8*)&Bs[cur][(wn * 64 + t * 16 + l15) * 64 +
                                         (((ks * 4 + quad) ^ l7) << 3)];
      }
      #pragma unroll
      for (int mt = 0; mt < 4; ++mt)
        #pragma unroll
        for (int nt = 0; nt < 4; ++nt)
          acc[mt][nt] = mfma16(af[mt], bfr[nt], acc[mt][nt]);
    }
  }

  if (blockIdx.y < 8) {
    // ---- Q / K scatter epilogue ----
    #pragma unroll
    for (int mt = 0; mt < 4; ++mt) {
      #pragma unroll
      for (int nt = 0; nt < 4; ++nt) {
        #pragma unroll
        for (int r = 0; r < 4; ++r) {
          int m = blockIdx.x * 128 + wm * 64 + mt * 16 + quad * 4 + r;
          int n = blockIdx.y * 128 + wn * 64 + nt * 16 + l15;
          float v = acc[mt][nt][r];
          int b = m >> 12, t = m & 4095;
          int h = (n >> 6) & 7, d = n & 63;
          size_t bh = (size_t)(b * 8 + h);
          if (n < 512)   // fold 1/sqrt(64) * log2(e) -> softmax in log2 domain
            Qo[bh * 262144 + (size_t)t * 64 + d] = (bf16_t)(v * 0.18033688f);
          else           // K fragment-linear
            Ko[bh * 262144 +
               (size_t)((((t >> 4) * 2 + (d >> 5)) * 512) +
                        ((((d & 31) >> 3) * 16 + (t & 15)) * 8) + (d & 7))] =
                (bf16_t)v;
        }
      }
    }
  } else {
    // ---- V epilogue: transpose through LDS (As region, 32 KB) ----
    __syncthreads();                       // everyone done reading As/Bs
    bf16_t* L = &As[0][0];                 // [n_local][m swizzled] 128x128
    #pragma unroll
    for (int mt = 0; mt < 4; ++mt)
      #pragma unroll
      for (int nt = 0; nt < 4; ++nt) {
        int n_l = wn * 64 + nt * 16 + l15;
        int mc  = wm * 8 + mt * 2 + (quad >> 1);     // m-chunk of 8
        bf16x4 v4;
        #pragma unroll
        for (int r = 0; r < 4; ++r) v4[r] = (bf16_t)acc[mt][nt][r];
        *(bf16x4*)&L[n_l * 128 + ((mc ^ (n_l & 15)) << 3) + (quad & 1) * 4] = v4;
      }
    __syncthreads();
    const int t0 = (blockIdx.x & 31) * 128;
    const int b  = blockIdx.x >> 5;
    #pragma unroll
    for (int i = 0; i < 8; ++i) {
      int c = tid + 256 * i;               // 0..2047: n_l = c>>4, tc = c&15
      int n_l = c >> 4, tc = c & 15;
      int h = ((blockIdx.y - 8) << 1) | (n_l >> 6);
      int d = n_l & 63;
      size_t bh = (size_t)(b * 8 + h);
      int base0 = (tc >> 2) * 32 + (tc & 3) * 4;
      bf16x4 lo = *(const bf16x4*)&L[n_l * 128 +
                     (((base0 >> 3) ^ (n_l & 15)) << 3) + (base0 & 7)];
      bf16x4 hi = *(const bf16x4*)&L[n_l * 128 +
                     ((((base0 + 16) >> 3) ^ (n_l & 15)) << 3) + (base0 & 7)];
      bf16x8 o;
      #pragma unroll
      for (int e = 0; e < 4; ++e) { o[e] = lo[e]; o[e + 4] = hi[e]; }
      int T = t0 + tc * 8;                 // t' base of this 8-chunk
      *(bf16x8*)&Vto[bh * 262144 +
                     (size_t)((((T >> 5) * 4 + (d >> 4)) * 512) +
                              ((((T >> 3) & 3) * 16 + (d & 15)) * 8))] = o;
    }
  }
}

// ---------------- output GEMM: out(8192,512) = Ob(8192,512) * Wo(512,512)^T ----
__global__ __launch_bounds__(256) void gemm_out(
    const bf16_t* __restrict__ A, const bf16_t* __restrict__ B,
    float* __restrict__ Cf)
{
  __shared__ __align__(16) bf16_t As[2][64 * 64];
  __shared__ __align__(16) bf16_t Bs[2][128 * 64];
  const int tid  = threadIdx.x;
  const int lane = tid & 63;
  const int w    = tid >> 6;               // 0..3, owns n-range w*32..+32
  const int quad = lane >> 4;
  const int l15  = lane & 15;
  const int l7   = lane & 7;

  floatx4 acc[4][2];
  #pragma unroll
  for (int i = 0; i < 4; ++i)
    #pragma unroll
    for (int j = 0; j < 2; ++j)
      acc[i][j] = (floatx4){0.f, 0.f, 0.f, 0.f};

  const bf16_t* Ab = A + (size_t)blockIdx.x * 64 * 512;
  const bf16_t* Bb = B + (size_t)blockIdx.y * 128 * 512;

  auto stage = [&](int buf, int k0) {
    #pragma unroll
    for (int i = 0; i < 2; ++i) {          // A: 512 chunks
      int c = tid + 256 * i;
      int row = c >> 3, colc = c & 7;
      GLDS16(&Ab[(size_t)row * 512 + k0 + ((colc ^ (row & 7)) << 3)],
             &As[buf][c * 8]);
    }
    #pragma unroll
    for (int i = 0; i < 4; ++i) {          // B: 1024 chunks
      int c = tid + 256 * i;
      int row = c >> 3, colc = c & 7;
      GLDS16(&Bb[(size_t)row * 512 + k0 + ((colc ^ (row & 7)) << 3)],
             &Bs[buf][c * 8]);
    }
  };

  stage(0, 0);
  for (int it = 0; it < 8; ++it) {
    const int cur = it & 1;
    __syncthreads();
    if (it + 1 < 8) stage(cur ^ 1, (it + 1) << 6);
    #pragma unroll
    for (int ks = 0; ks < 2; ++ks) {
      bf16x8 af[4], bfr[2];
      #pragma unroll
      for (int t = 0; t < 4; ++t)
        af[t]  = *(const bf16x8*)&As[cur][(t * 16 + l15) * 64 +
                                         (((ks * 4 + quad) ^ l7) << 3)];
      #pragma unroll
      for (int t = 0; t < 2; ++t)
        bfr[t] = *(const bf16x8*)&Bs[cur][(w * 32 + t * 16 + l15) * 64 +
                                         (((ks * 4 + quad) ^ l7) << 3)];
      #pragma unroll
      for (int mt = 0; mt < 4; ++mt)
        #pragma unroll
        for (int nt = 0; nt < 2; ++nt)
          acc[mt][nt] = mfma16(af[mt], bfr[nt], acc[mt][nt]);
    }
  }

  #pragma unroll
  for (int mt = 0; mt < 4; ++mt)
    #pragma unroll
    for (int nt = 0; nt < 2; ++nt)
      #pragma unroll
      for (int r = 0; r < 4; ++r) {
        int m = blockIdx.x * 64 + mt * 16 + quad * 4 + r;
        int n = blockIdx.y * 128 + w * 32 + nt * 16 + l15;
        Cf[(size_t)m * 512 + n] = acc[mt][nt][r];
      }
}

// ---- causal flash attention: register-direct, balanced barrier-free waves ----
// 256 blocks x 512 threads (8 waves), 1 block/CU. Waves = {qh} x {kq in 0..3};
// each wave runs 64q x 64k units stepping k64 by 4, and processes tile qtA then
// qtB SEQUENTIALLY -> per-wave iterations = (2qtA+qh-kq)/4 + (2qtB+qh-kq)/4
// ~ 15.75 +- 1, uniform across waves AND blocks (R9's tail: qtB waves retired
// early -> Occupancy 15.6%, SIMD-mates lost). K/V read DIRECTLY from global in
// fragment-linear layout (coalesced dwordx4, L2-resident: 1 MB/bh, 2 bh/XCD).
// Zero main-loop barriers: waves drift so exp2 (trans) of one wave overlaps
// MFMA of its SIMD-mate. Epilogue per tile: 4 kq-partials to LDS (133 KB,
// epilogue-only), all-thread merge + normalize + direct Og store (R8's
// verified pattern). No-max log2-domain softmax (scores bounded, fp32-safe).
__global__ __launch_bounds__(512, 1) void attn_kernel(
    const bf16_t* __restrict__ Qg, const bf16_t* __restrict__ Kf,
    const bf16_t* __restrict__ Vf, bf16_t* __restrict__ Og)
{
  // PART[qh][kq][64q][64d] f32 = 131072 B ; PL[qh][kq][64] f32 = 2048 B
  __shared__ __align__(16) bf16_t smem[66560];   // 133,120 B

  const int tid  = threadIdx.x;
  const int lane = tid & 63;
  const int w    = tid >> 6;               // 0..7
  const int qh   = w >> 2;                 // q 64-half of the 128-row tile
  const int kq   = w & 3;                  // k64 residue class this wave owns
  const int quad = lane >> 4;
  const int l15  = lane & 15;

  const int id = blockIdx.x;               // 0..255
  const int bh = 2 * (id & 7) + ((id >> 3) & 1);   // 2 bh per XCD (L2 reuse)
  const int x  = id >> 4;                  // 0..15
  const int qtA = 31 - x, qtB = x;
  const size_t bh_off = (size_t)bh * 262144;
  const int b = bh >> 3, h = bh & 7;

  const bf16_t* Kb_ = Kf + bh_off;
  const bf16_t* Vb_ = Vf + bh_off;
  const floatx4 z4 = (floatx4){0.f, 0.f, 0.f, 0.f};
  bf16x8 ones;
  #pragma unroll
  for (int i = 0; i < 8; ++i) ones[i] = (bf16_t)1.0f;

  for (int ph = 0; ph < 2; ++ph) {
    const int qt   = ph ? qtB : qtA;
    const int q64  = 2 * qt + qh;          // wave's 64-row q-block index
    const int qbase = qt * 128 + qh * 64;

    // Q fragments (pre-scaled by 0.125*log2e): 4 q-blocks of 16 rows
    bf16x8 aq0[4], aq1[4];
    #pragma unroll
    for (int qb = 0; qb < 4; ++qb) {
      const bf16_t* Qp = Qg + bh_off + (size_t)(qbase + qb * 16 + l15) * 64;
      aq0[qb] = *(const bf16x8*)&Qp[quad * 8];
      aq1[qb] = *(const bf16x8*)&Qp[32 + quad * 8];
    }

    floatx4 acc_o[4][4], acc_l[4];
    #pragma unroll
    for (int qb = 0; qb < 4; ++qb) {
      #pragma unroll
      for (int dt = 0; dt < 4; ++dt) acc_o[qb][dt] = (floatx4){0.f, 0.f, 0.f, 0.f};
      acc_l[qb] = (floatx4){0.f, 0.f, 0.f, 0.f};
    }

    for (int k64 = kq; k64 <= q64; k64 += 4) {
      const bf16_t* Kp = Kb_ + (size_t)k64 * 4096;   // 8 K-frags of 512 elems
      const bf16_t* Vp = Vb_ + (size_t)k64 * 4096;   // 8 V-frags of 512 elems
      // ---- K fragment loads: coalesced, L2-hot ----
      bf16x8 bk0[4], bk1[4];
      #pragma unroll
      for (int nt = 0; nt < 4; ++nt) {
        bk0[nt] = *(const bf16x8*)&Kp[(nt * 2 + 0) * 512 + lane * 8];
        bk1[nt] = *(const bf16x8*)&Kp[(nt * 2 + 1) * 512 + lane * 8];
      }
      // ---- S^T = K Q^T : 64 k-rows x 64 q-cols ----
      floatx4 s[4][4];                     // [qb][nt]
      #pragma unroll
      for (int nt = 0; nt < 4; ++nt) {
        s[0][nt] = mfma16(bk0[nt], aq0[0], z4);
        s[1][nt] = mfma16(bk0[nt], aq0[1], z4);
        s[2][nt] = mfma16(bk0[nt], aq0[2], z4);
        s[3][nt] = mfma16(bk0[nt], aq0[3], z4);
      }
      #pragma unroll
      for (int nt = 0; nt < 4; ++nt)
        #pragma unroll
        for (int qb = 0; qb < 4; ++qb)
          s[qb][nt] = mfma16(bk1[nt], aq1[qb], s[qb][nt]);
      // ---- V fragment loads (latency hides under exp2) ----
      bf16x8 av[2][4];
      #pragma unroll
      for (int kc = 0; kc < 2; ++kc)
        #pragma unroll
        for (int dt = 0; dt < 4; ++dt)
          av[kc][dt] = *(const bf16x8*)&Vp[(kc * 4 + dt) * 512 + lane * 8];
      // ---- no-max softmax, log2 domain ----
      if (k64 == q64) {                    // diagonal 64-block: mask k > q
        #pragma unroll
        for (int qb = 0; qb < 4; ++qb)
          #pragma unroll
          for (int nt = 0; nt < 4; ++nt)
            #pragma unroll
            for (int r = 0; r < 4; ++r)
              if (nt * 16 + quad * 4 + r > qb * 16 + l15)
                s[qb][nt][r] = -3.0e38f;
      }
      #pragma unroll
      for (int qb = 0; qb < 4; ++qb)
        #pragma unroll
        for (int nt = 0; nt < 4; ++nt)
          #pragma unroll
          for (int r = 0; r < 4; ++r)
            s[qb][nt][r] = __builtin_amdgcn_exp2f(s[qb][nt][r]);
      // ---- PV: O^T += V^T P^T ; l += 1^T P^T ----
      #pragma unroll
      for (int kc = 0; kc < 2; ++kc) {
        bf16x8 pb[4];
        #pragma unroll
        for (int qb = 0; qb < 4; ++qb)
          #pragma unroll
          for (int r = 0; r < 4; ++r) {
            pb[qb][r]     = (bf16_t)s[qb][kc * 2][r];
            pb[qb][r + 4] = (bf16_t)s[qb][kc * 2 + 1][r];
          }
        #pragma unroll
        for (int qb = 0; qb < 4; ++qb)
          acc_l[qb] = mfma16(ones, pb[qb], acc_l[qb]);
        #pragma unroll
        for (int dt = 0; dt < 4; ++dt)
          #pragma unroll
          for (int qb = 0; qb < 4; ++qb)
            acc_o[qb][dt] = mfma16(av[kc][dt], pb[qb], acc_o[qb][dt]);
      }
    }

    // ---- epilogue: 4 kq-partials -> LDS, all-thread merge + store ----
    {
      float* Pq = (float*)&smem[0] + (qh * 4 + kq) * 4096;   // [64q][64d]
      float* PL = (float*)&smem[65536];                      // [qh][kq][64]
      #pragma unroll
      for (int qb = 0; qb < 4; ++qb) {
        int q = qb * 16 + l15;
        #pragma unroll
        for (int dt = 0; dt < 4; ++dt)
          *(floatx4*)&Pq[q * 64 + (((dt * 4 + quad) ^ l15) << 2)] = acc_o[qb][dt];
        if (quad == 0) PL[(qh * 4 + kq) * 64 + q] = acc_l[qb][0];
      }
    }
    __syncthreads();
    #pragma unroll
    for (int i = 0; i < 2; ++i) {          // 1024 cells: (qh, q, 8d-chunk)
      int a = tid + 512 * i;
      int qh_e = a >> 9, rem = a & 511;
      int q = rem >> 3, c8 = rem & 7;
      const float* Pq = (const float*)&smem[0] + qh_e * 16384;
      const float* PL = (const float*)&smem[65536] + qh_e * 256;
      float s0[8] = {0.f, 0.f, 0.f, 0.f, 0.f, 0.f, 0.f, 0.f};
      float suml = 0.f;
      #pragma unroll
      for (int k2 = 0; k2 < 4; ++k2) {
        const float* Pk = Pq + k2 * 4096 + q * 64;
        floatx4 u0 = *(const floatx4*)&Pk[((c8 * 2)     ^ (q & 15)) << 2];
        floatx4 u1 = *(const floatx4*)&Pk[((c8 * 2 + 1) ^ (q & 15)) << 2];
        #pragma unroll
        for (int r = 0; r < 4; ++r) { s0[r] += u0[r]; s0[4 + r] += u1[r]; }
        suml += PL[k2 * 64 + q];
      }
      float rl = 1.0f / suml;
      bf16x8 o;
      #pragma unroll
      for (int e = 0; e < 8; ++e) o[e] = (bf16_t)(s0[e] * rl);
      int row = qt * 128 + qh_e * 64 + q;
      *(bf16x8*)&Og[((size_t)b * 4096 + row) * 512 + h * 64 + c8 * 8] = o;
    }
    if (ph == 0) __syncthreads();          // PART reads done before B partials
  }
}

// ---------------- launcher ----------------
extern "C" void kernel_launch(void* const* d_in, const int* in_sizes, int n_in,
                              void* d_out, int out_size, void* d_ws, size_t ws_size,
                              hipStream_t stream) {
  const float* x    = (const float*)d_in[0];   // (2,4096,512)
  const float* wqkv = (const float*)d_in[1];   // (1536,512)
  const float* wo   = (const float*)d_in[2];   // (512,512)
  float* out = (float*)d_out;                  // (2,4096,512) fp32

  char* ws = (char*)d_ws;
  bf16_t* xb    = (bf16_t*)(ws);                 //  8 MB (reused as Ob after gemm1)
  bf16_t* wqkvb = (bf16_t*)(ws + 8388608);       //  1.5 MB
  bf16_t* wob   = (bf16_t*)(ws + 9961472);       //  0.5 MB
  bf16_t* Qb    = (bf16_t*)(ws + 10485760);      //  8 MB  [bh][t][64], pre-scaled
  bf16_t* Kfb   = (bf16_t*)(ws + 18874368);      //  8 MB  K fragment-linear
  bf16_t* Vfb   = (bf16_t*)(ws + 27262976);      //  8 MB  V^T fragment-linear
  bf16_t* Ob    = xb;                            //  alias: gemm1 done with xb
  // total 35,651,584 bytes

  cvt_all_kernel<<<5120, 256, 0, stream>>>(x, wqkv, wo, xb, wqkvb, wob);

  gemm_qkv<<<dim3(64, 12), 256, 0, stream>>>(xb, wqkvb, Qb, Kfb, Vfb);
  attn_kernel<<<dim3(256), 512, 0, stream>>>(Qb, Kfb, Vfb, Ob);
  gemm_out<<<dim3(128, 4), 256, 0, stream>>>(Ob, wob, out);
}